// Round 13
// baseline (117.946 us; speedup 1.0000x reference)
//
#include <hip/hip_runtime.h>

#define N 512
#define D 128
#define TS 32
// 1000 * log2(e): sigmoid(x/K) = 1/(1+exp(-x*1000)) = 1/(1+exp2(-x*SCALE))
#define RS_SCALE 1442.6950408889634f
// bucket width == far-threshold 18 (sigmoid saturated to 0/1 within 2^-18)
#define W_INV (1.0f / 18.0f)
#define B_OFF 1530.0f
#define PADV -1600.0f   // pad sorts below all real rs (>= -1442.7), bucket 0
#define NB 172
// PROBE: window-summation dilation factor (reps 2..WREP recompute the same
// sums from opaque-zero inits; result identical, duration = base + (WREP-1)*win)
#define WREP 8

static __device__ __forceinline__ float rcp_fast(float x) {
    return __builtin_amdgcn_rcpf(x);
}
static __device__ __forceinline__ float exp2_fast(float x) {
    return __builtin_amdgcn_exp2f(x);
}

// ---------------- K1: fused row-norms + scaled cosine-sim GEMM --------------
// 16x16 grid of 32x32 tiles (256 blocks), 256 threads, 2x2 microtile.
__global__ __launch_bounds__(256) void map_sim_kernel(
    const float* __restrict__ x, float* __restrict__ rs,
    int* __restrict__ ticket)
{
    const int bi = blockIdx.x, bj = blockIdx.y, t = threadIdx.x;
    __shared__ float As[TS * D], Bs[TS * D];
    __shared__ float ssA[TS], ssB[TS];
    __shared__ float invA[TS], invB[TS];

    if (bi == 0 && bj == 0 && t == 0) *ticket = 0;  // reset fence counter

    const int lane = t & 63;
#pragma unroll
    for (int r = 0; r < 4; ++r) {
        int ch = t + 256 * r;            // [0,1024): 32 rows x 32 float4
        int row = ch >> 5, c4 = ch & 31; // 32 consecutive lanes share a row
        int sw = (c4 ^ (row >> 1)) << 2; // swizzle: frag reads spread banks
        float4 va = *(const float4*)(x + (bi * TS + row) * D + c4 * 4);
        *(float4*)(As + row * D + sw) = va;
        float pa = va.x * va.x + va.y * va.y + va.z * va.z + va.w * va.w;
        float4 vb = *(const float4*)(x + (bj * TS + row) * D + c4 * 4);
        *(float4*)(Bs + row * D + sw) = vb;
        float pb = vb.x * vb.x + vb.y * vb.y + vb.z * vb.z + vb.w * vb.w;
#pragma unroll
        for (int off = 16; off; off >>= 1) {  // reduce within 32-lane row group
            pa += __shfl_xor(pa, off);
            pb += __shfl_xor(pb, off);
        }
        if ((lane & 31) == 0) { ssA[row] = pa; ssB[row] = pb; }
    }
    __syncthreads();
    if (t < TS)          invA[t] = rcp_fast(fmaxf(sqrtf(ssA[t]), 1e-8f));
    else if (t < 2 * TS) invB[t - TS] = rcp_fast(fmaxf(sqrtf(ssB[t - TS]), 1e-8f));
    __syncthreads();

    const int tx = t & 15, ty = t >> 4;
    float acc00 = 0.f, acc01 = 0.f, acc10 = 0.f, acc11 = 0.f;
#pragma unroll 4
    for (int k4 = 0; k4 < D / 4; ++k4) {
        float4 a0 = *(const float4*)(As + (2 * ty) * D + ((k4 ^ ty) << 2));
        float4 a1 = *(const float4*)(As + (2 * ty + 1) * D + ((k4 ^ ty) << 2));
        float4 b0 = *(const float4*)(Bs + (2 * tx) * D + ((k4 ^ tx) << 2));
        float4 b1 = *(const float4*)(Bs + (2 * tx + 1) * D + ((k4 ^ tx) << 2));
        acc00 = fmaf(a0.x, b0.x, acc00); acc00 = fmaf(a0.y, b0.y, acc00);
        acc00 = fmaf(a0.z, b0.z, acc00); acc00 = fmaf(a0.w, b0.w, acc00);
        acc01 = fmaf(a0.x, b1.x, acc01); acc01 = fmaf(a0.y, b1.y, acc01);
        acc01 = fmaf(a0.z, b1.z, acc01); acc01 = fmaf(a0.w, b1.w, acc01);
        acc10 = fmaf(a1.x, b0.x, acc10); acc10 = fmaf(a1.y, b0.y, acc10);
        acc10 = fmaf(a1.z, b0.z, acc10); acc10 = fmaf(a1.w, b0.w, acc10);
        acc11 = fmaf(a1.x, b1.x, acc11); acc11 = fmaf(a1.y, b1.y, acc11);
        acc11 = fmaf(a1.z, b1.z, acc11); acc11 = fmaf(a1.w, b1.w, acc11);
    }

    const float sA0 = invA[2 * ty] * RS_SCALE;
    const float sA1 = invA[2 * ty + 1] * RS_SCALE;
    const float sB0 = invB[2 * tx], sB1 = invB[2 * tx + 1];
    const int gr = bi * TS + 2 * ty, gc = bj * TS + 2 * tx;
    *(float2*)(rs + gr * N + gc) =
        make_float2(acc00 * sA0 * sB0, acc01 * sA0 * sB1);
    *(float2*)(rs + (gr + 1) * N + gc) =
        make_float2(acc10 * sA1 * sB0, acc11 * sA1 * sB1);
}

// ---------------- K2: counting-sort + windowed AP (window dilated x8) -------
__global__ __launch_bounds__(256) void map_ap_kernel(
    const float* __restrict__ rs, const int* __restrict__ tgt,
    float2* __restrict__ av, int* __restrict__ ticket,
    float* __restrict__ out)
{
    const int i = blockIdx.x, t = threadIdx.x;
    const int lane = t & 63;
    __shared__ int hist[256];   // packed (count<<10)|gtcount -> inclusive scan
    __shared__ int offs[NB];
    __shared__ int wtot[4];
    __shared__ unsigned gbits[16];            // gt bitmask by sorted position
    __shared__ __align__(16) float skey[N];   // bucket-sorted keys
    __shared__ float red[8];
    __shared__ int amLast;

    // issue global loads first (latency overlaps LDS init)
    const int ti = tgt[i];
    const float v0raw = rs[i * N + t];
    const float v1raw = rs[i * N + t + 256];
    const int tg0 = tgt[t], tg1 = tgt[t + 256];

    hist[t] = 0;
    if (t < NB) offs[t] = 0;
    if (t < 16) gbits[t] = 0u;

    float val[2]; int gti[2], q[2];
    val[0] = (t == i) ? PADV : v0raw;
    val[1] = (t + 256 == i) ? PADV : v1raw;
    gti[0] = (t != i && tg0 == ti) ? 1 : 0;
    gti[1] = (t + 256 != i && tg1 == ti) ? 1 : 0;
#pragma unroll
    for (int e = 0; e < 2; ++e) {
        int qq = (int)((val[e] + B_OFF) * W_INV);
        q[e] = max(0, min(NB - 1, qq));
    }
    __syncthreads();
    atomicAdd(&hist[q[0]], (1 << 10) | gti[0]);
    atomicAdd(&hist[q[1]], (1 << 10) | gti[1]);
    __syncthreads();

    // wave-level inclusive scan of hist[0..255] (packed fields scan together)
    int v = hist[t];
#pragma unroll
    for (int off = 1; off < 64; off <<= 1) {
        int u = __shfl_up(v, off);
        if (lane >= off) v += u;
    }
    if (lane == 63) wtot[t >> 6] = v;
    __syncthreads();
    {
        int w = t >> 6, add = 0;
        if (w > 0) add += wtot[0];
        if (w > 1) add += wtot[1];
        if (w > 2) add += wtot[2];
        hist[t] = v + add;
    }
    __syncthreads();

    // scatter: keys to skey[], gt flags to bitmask
#pragma unroll
    for (int e = 0; e < 2; ++e) {
        int base = (q[e] > 0) ? (hist[q[e] - 1] >> 10) : 0;
        int pos = base + atomicAdd(&offs[q[e]], 1);
        skey[pos] = val[e];
        if (gti[e]) atomicOr(&gbits[pos >> 5], 1u << (pos & 31));
    }
    __syncthreads();

    const int totGt = hist[NB - 1] & 1023;
    const float4* sk4 = (const float4*)skey;

    float apAcc = 0.f, npAcc = 0.f;
#pragma unroll
    for (int ri = 0; ri < 2; ++ri) {
        const int p = t + 256 * ri;     // sorted position
        const float rj = skey[p];
        const float gtj = (float)((gbits[p >> 5] >> (p & 31)) & 1u);
        int qj = (int)((rj + B_OFF) * W_INV);
        qj = max(0, min(NB - 1, qj));
        // wave-uniform bounds (positions consecutive -> qj monotonic in lane)
        const int qlo = __shfl(qj, 0);
        const int qhi = __shfl(qj, 63);
        const int lo = (qlo > 1) ? (hist[qlo - 2] >> 10) : 0;
        const int e1 = min(qhi + 1, NB - 1);
        const int hi = hist[e1] >> 10;

        const float dInit = (float)(N - hi);   // far-above: exactly 1 each
        const float gInit = (float)(totGt - (hist[e1] & 1023));

        // ---- PROBE: recompute the window sums WREP times; every rep is
        // identical & correct; opaque zeros + memory clobber defeat CSE ----
        float dsum = 0.f, gsum = 0.f;
        for (int rep = 0; rep < WREP; ++rep) {
            asm volatile("" ::: "memory");  // force LDS re-reads each rep
            float d0 = 0.f, d1 = 0.f, d2 = 0.f, d3 = 0.f;
            float g0 = 0.f, g1 = 0.f, g2 = 0.f, g3 = 0.f;
            asm volatile("" : "+v"(d0), "+v"(d1), "+v"(d2), "+v"(d3),
                             "+v"(g0), "+v"(g1), "+v"(g2), "+v"(g3));
            float ds = dInit, gs = gInit;
            int k = lo & ~7;            // elems in [k, lo) saturate to 0: exact
            for (; k + 8 <= hi; k += 8) {
                float4 ka = sk4[k >> 2];        // broadcast (wave-uniform)
                float4 kb = sk4[(k >> 2) + 1];
                unsigned gw = (gbits[k >> 5] >> (k & 31)) & 0xffu;
                float s0 = rcp_fast(1.f + exp2_fast(rj - ka.x));
                float s1 = rcp_fast(1.f + exp2_fast(rj - ka.y));
                float s2 = rcp_fast(1.f + exp2_fast(rj - ka.z));
                float s3 = rcp_fast(1.f + exp2_fast(rj - ka.w));
                float s4 = rcp_fast(1.f + exp2_fast(rj - kb.x));
                float s5 = rcp_fast(1.f + exp2_fast(rj - kb.y));
                float s6 = rcp_fast(1.f + exp2_fast(rj - kb.z));
                float s7 = rcp_fast(1.f + exp2_fast(rj - kb.w));
                d0 += s0 + s4; d1 += s1 + s5; d2 += s2 + s6; d3 += s3 + s7;
                g0 += ((gw      ) & 1u) ? s0 : 0.f;
                g1 += ((gw >> 1u) & 1u) ? s1 : 0.f;
                g2 += ((gw >> 2u) & 1u) ? s2 : 0.f;
                g3 += ((gw >> 3u) & 1u) ? s3 : 0.f;
                g0 += ((gw >> 4u) & 1u) ? s4 : 0.f;
                g1 += ((gw >> 5u) & 1u) ? s5 : 0.f;
                g2 += ((gw >> 6u) & 1u) ? s6 : 0.f;
                g3 += ((gw >> 7u) & 1u) ? s7 : 0.f;
            }
            ds += (d0 + d1) + (d2 + d3);
            gs += (g0 + g1) + (g2 + g3);
            for (; k < hi; ++k) {       // scalar tail (<8 iters)
                float s = rcp_fast(1.f + exp2_fast(rj - skey[k]));
                ds += s;
                gs += ((gbits[k >> 5] >> (k & 31)) & 1u) ? s : 0.f;
            }
            dsum = ds; gsum = gs;
            asm volatile("" :: "v"(dsum), "v"(gsum));  // sink each rep
        }

        apAcc += gtj * gsum * rcp_fast(dsum + 0.5f);
        npAcc += gtj;
    }

    // block reduction (4 waves)
#pragma unroll
    for (int off = 32; off; off >>= 1) {
        apAcc += __shfl_down(apAcc, off);
        npAcc += __shfl_down(npAcc, off);
    }
    if (lane == 0) { red[(t >> 6) * 2] = apAcc; red[(t >> 6) * 2 + 1] = npAcc; }
    __syncthreads();
    if (t == 0) {
        float A = red[0] + red[2] + red[4] + red[6];
        float P = red[1] + red[3] + red[5] + red[7];
        av[i] = make_float2((P > 0.f) ? (A * rcp_fast(P)) : 0.f,
                            (P > 0.f) ? 1.f : 0.f);
        __threadfence();                       // release av[i]
        int old = atomicAdd(ticket, 1);
        amLast = (old == (int)gridDim.x - 1) ? 1 : 0;
    }
    __syncthreads();

    if (amLast) {  // last block (uniform) reduces av[] and writes out
        __threadfence();                       // acquire
        float2 p0 = av[t], p1 = av[t + 256];
        float a = p0.x + p1.x, vv = p0.y + p1.y;
#pragma unroll
        for (int off = 32; off; off >>= 1) {
            a += __shfl_down(a, off);
            vv += __shfl_down(vv, off);
        }
        if (lane == 0) { red[(t >> 6) * 2] = a; red[(t >> 6) * 2 + 1] = vv; }
        __syncthreads();
        if (t == 0) {
            float A = red[0] + red[2] + red[4] + red[6];
            float V = red[1] + red[3] + red[5] + red[7];
            out[0] = 1.0f - A * rcp_fast(V);
        }
    }
}

extern "C" void kernel_launch(void* const* d_in, const int* in_sizes, int n_in,
                              void* d_out, int out_size, void* d_ws, size_t ws_size,
                              hipStream_t stream) {
    const float* x = (const float*)d_in[0];
    const int* tgt = (const int*)d_in[1];
    float* out = (float*)d_out;

    float* rs = (float*)d_ws;                                 // 1 MB
    float2* av = (float2*)((char*)d_ws + N * N * 4);          // 4 KB
    int* ticket = (int*)((char*)d_ws + N * N * 4 + N * 8);    // 4 B

    map_sim_kernel<<<dim3(N / TS, N / TS), 256, 0, stream>>>(x, rs, ticket);
    map_ap_kernel<<<N, 256, 0, stream>>>(rs, tgt, av, ticket, out);
}

// Round 14
// 29.337 us; speedup vs baseline: 4.0204x; 4.0204x over previous
//
#include <hip/hip_runtime.h>

#define N 512
#define D 128
// 1000 * log2(e): sigmoid(x/K) = 1/(1+exp(-x*1000)) = 1/(1+exp2(-x*SCALE))
#define RS_SCALE 1442.6950408889634f
// bucket width == far-threshold 18 (sigmoid saturated to 0/1 within 2^-18)
#define W_INV (1.0f / 18.0f)
#define B_OFF 1530.0f
#define PADV -1600.0f   // pad sorts below all real rs (>= -1442.7), bucket 0
#define NB 172

static __device__ __forceinline__ float rcp_fast(float x) {
    return __builtin_amdgcn_rcpf(x);
}
static __device__ __forceinline__ float exp2_fast(float x) {
    return __builtin_amdgcn_exp2f(x);
}

// ---------------- K1: raw-dot GEMM x.x^T (16x32 tiles, 512 blocks) ----------
// No norms here: diag rs[c][c] = ||x_c||^2, consumed by K2. 256 threads,
// 2x1 microtile. XOR-swizzled LDS granules -> conflict-free reads.
__global__ __launch_bounds__(256) void map_sim_kernel(
    const float* __restrict__ x, float* __restrict__ rs,
    int* __restrict__ ticket)
{
    const int bi = blockIdx.x;   // 32 row-panels of 16
    const int bj = blockIdx.y;   // 16 col-panels of 32
    const int t = threadIdx.x;
    __shared__ float As[16 * D];
    __shared__ float Bs[32 * D];

    if (bi == 0 && bj == 0 && t == 0) *ticket = 0;  // reset fence counter

    // stage A (16 rows x 32 granules = 512) and B (32 rows = 1024 granules)
#pragma unroll
    for (int s = 0; s < 2; ++s) {
        int ch = t + 256 * s;
        int row = ch >> 5, c4 = ch & 31;
        *(float4*)(As + row * D + ((c4 ^ row) << 2)) =
            *(const float4*)(x + (bi * 16 + row) * D + c4 * 4);
    }
#pragma unroll
    for (int s = 0; s < 4; ++s) {
        int ch = t + 256 * s;
        int row = ch >> 5, c4 = ch & 31;
        *(float4*)(Bs + row * D + ((c4 ^ row) << 2)) =
            *(const float4*)(x + (bj * 32 + row) * D + c4 * 4);
    }
    __syncthreads();

    const int c = t & 31;        // B column within tile
    const int rp = t >> 5;       // A row-pair (8 pairs = 16 rows)
    const int ra0 = 2 * rp, ra1 = 2 * rp + 1;
    float acc0 = 0.f, acc1 = 0.f;
#pragma unroll 8
    for (int k4 = 0; k4 < D / 4; ++k4) {
        float4 b = *(const float4*)(Bs + c * D + ((k4 ^ c) << 2));
        float4 a0 = *(const float4*)(As + ra0 * D + ((k4 ^ ra0) << 2));
        float4 a1 = *(const float4*)(As + ra1 * D + ((k4 ^ ra1) << 2));
        acc0 = fmaf(a0.x, b.x, acc0); acc0 = fmaf(a0.y, b.y, acc0);
        acc0 = fmaf(a0.z, b.z, acc0); acc0 = fmaf(a0.w, b.w, acc0);
        acc1 = fmaf(a1.x, b.x, acc1); acc1 = fmaf(a1.y, b.y, acc1);
        acc1 = fmaf(a1.z, b.z, acc1); acc1 = fmaf(a1.w, b.w, acc1);
    }
    const int gc = bj * 32 + c;
    rs[(bi * 16 + ra0) * N + gc] = acc0;
    rs[(bi * 16 + ra1) * N + gc] = acc1;
}

// ---------------- K2: counting-sort + windowed AP (512 thr, 1 pos/thread) ---
__global__ __launch_bounds__(512) void map_ap_kernel(
    const float* __restrict__ rs, const int* __restrict__ tgt,
    float2* __restrict__ av, int* __restrict__ ticket,
    float* __restrict__ out)
{
    const int i = blockIdx.x, t = threadIdx.x;
    const int lane = t & 63;
    __shared__ int hist[256];   // packed (count<<10)|gtcount -> inclusive scan
    __shared__ int offs[NB];
    __shared__ int wtot[4];
    __shared__ unsigned gbits[16];            // gt bitmask by sorted position
    __shared__ __align__(16) float skey[N];   // bucket-sorted keys
    __shared__ float red[16];
    __shared__ int amLast;

    // issue global loads first (latency overlaps LDS init)
    const int ti = tgt[i];
    const float draw = rs[i * N + t];
    const float ssT = rs[t * N + t];     // diag = ||x_t||^2 (L2-hot)
    const float ssI = rs[i * N + i];
    const int tgT = tgt[t];

    if (t < 256) hist[t] = 0;
    if (t < NB) offs[t] = 0;
    if (t < 16) gbits[t] = 0u;

    const bool self = (t == i);
    const float invT = rcp_fast(fmaxf(sqrtf(ssT), 1e-8f));
    const float invI = rcp_fast(fmaxf(sqrtf(ssI), 1e-8f));
    const float val = self ? PADV : draw * invT * invI * RS_SCALE;
    const int gti = (!self && tgT == ti) ? 1 : 0;
    int q = (int)((val + B_OFF) * W_INV);
    q = max(0, min(NB - 1, q));
    __syncthreads();
    atomicAdd(&hist[q], (1 << 10) | gti);
    __syncthreads();

    // wave-level inclusive scan of hist[0..255] (waves 0-3, packed fields)
    int v = (t < 256) ? hist[t] : 0;
#pragma unroll
    for (int off = 1; off < 64; off <<= 1) {
        int u = __shfl_up(v, off);
        if (lane >= off) v += u;
    }
    if (t < 256 && lane == 63) wtot[t >> 6] = v;
    __syncthreads();
    if (t < 256) {
        int w = t >> 6, add = 0;
        if (w > 0) add += wtot[0];
        if (w > 1) add += wtot[1];
        if (w > 2) add += wtot[2];
        hist[t] = v + add;
    }
    __syncthreads();

    // scatter: key to skey[], gt flag to bitmask
    {
        int base = (q > 0) ? (hist[q - 1] >> 10) : 0;
        int pos = base + atomicAdd(&offs[q], 1);
        skey[pos] = val;
        if (gti) atomicOr(&gbits[pos >> 5], 1u << (pos & 31));
    }
    __syncthreads();

    // windowed sigmoid AP, position p = t; 16-lane-group bounds
    const int totGt = hist[NB - 1] & 1023;
    const float4* sk4 = (const float4*)skey;

    const float rj = skey[t];
    const float gtj = (float)((gbits[t >> 5] >> (t & 31)) & 1u);
    int qj = (int)((rj + B_OFF) * W_INV);
    qj = max(0, min(NB - 1, qj));
    const int gl = lane & 48;            // first lane of 16-lane group
    const int qlo = __shfl(qj, gl);
    const int qhi = __shfl(qj, gl + 15);
    const int lo = (qlo > 1) ? (hist[qlo - 2] >> 10) : 0;
    const int e1 = min(qhi + 1, NB - 1);
    const int hi = hist[e1] >> 10;

    float dsum = (float)(N - hi);   // buckets >= qhi+2: exactly 1 each
    float gsum = (float)(totGt - (hist[e1] & 1023));

    float d0 = 0.f, d1 = 0.f, d2 = 0.f, d3 = 0.f;
    float g0 = 0.f, g1 = 0.f, g2 = 0.f, g3 = 0.f;
    int k = lo & ~7;                // elems in [k, lo) saturate to 0: exact
    for (; k + 8 <= hi; k += 8) {
        float4 ka = sk4[k >> 2];        // group-uniform address
        float4 kb = sk4[(k >> 2) + 1];
        unsigned gw = (gbits[k >> 5] >> (k & 31)) & 0xffu;
        float s0 = rcp_fast(1.f + exp2_fast(rj - ka.x));
        float s1 = rcp_fast(1.f + exp2_fast(rj - ka.y));
        float s2 = rcp_fast(1.f + exp2_fast(rj - ka.z));
        float s3 = rcp_fast(1.f + exp2_fast(rj - ka.w));
        float s4 = rcp_fast(1.f + exp2_fast(rj - kb.x));
        float s5 = rcp_fast(1.f + exp2_fast(rj - kb.y));
        float s6 = rcp_fast(1.f + exp2_fast(rj - kb.z));
        float s7 = rcp_fast(1.f + exp2_fast(rj - kb.w));
        d0 += s0 + s4; d1 += s1 + s5; d2 += s2 + s6; d3 += s3 + s7;
        g0 += ((gw      ) & 1u) ? s0 : 0.f;
        g1 += ((gw >> 1u) & 1u) ? s1 : 0.f;
        g2 += ((gw >> 2u) & 1u) ? s2 : 0.f;
        g3 += ((gw >> 3u) & 1u) ? s3 : 0.f;
        g0 += ((gw >> 4u) & 1u) ? s4 : 0.f;
        g1 += ((gw >> 5u) & 1u) ? s5 : 0.f;
        g2 += ((gw >> 6u) & 1u) ? s6 : 0.f;
        g3 += ((gw >> 7u) & 1u) ? s7 : 0.f;
    }
    dsum += (d0 + d1) + (d2 + d3);
    gsum += (g0 + g1) + (g2 + g3);
    for (; k < hi; ++k) {           // scalar tail (<8 iters)
        float s = rcp_fast(1.f + exp2_fast(rj - skey[k]));
        dsum += s;
        gsum += ((gbits[k >> 5] >> (k & 31)) & 1u) ? s : 0.f;
    }

    float apAcc = gtj * gsum * rcp_fast(dsum + 0.5f);  // pad thread: gtj = 0
    float npAcc = gtj;

    // block reduction (8 waves)
#pragma unroll
    for (int off = 32; off; off >>= 1) {
        apAcc += __shfl_down(apAcc, off);
        npAcc += __shfl_down(npAcc, off);
    }
    if (lane == 0) { red[(t >> 6) * 2] = apAcc; red[(t >> 6) * 2 + 1] = npAcc; }
    __syncthreads();
    if (t == 0) {
        float A = 0.f, P = 0.f;
#pragma unroll
        for (int kk = 0; kk < 8; ++kk) { A += red[2 * kk]; P += red[2 * kk + 1]; }
        av[i] = make_float2((P > 0.f) ? (A * rcp_fast(P)) : 0.f,
                            (P > 0.f) ? 1.f : 0.f);
        __threadfence();                       // release av[i]
        int old = atomicAdd(ticket, 1);
        amLast = (old == (int)gridDim.x - 1) ? 1 : 0;
    }
    __syncthreads();

    if (amLast) {  // last block (uniform) reduces av[] and writes out
        __threadfence();                       // acquire
        float2 p = av[t];
        float a = p.x, vv = p.y;
#pragma unroll
        for (int off = 32; off; off >>= 1) {
            a += __shfl_down(a, off);
            vv += __shfl_down(vv, off);
        }
        if (lane == 0) { red[(t >> 6) * 2] = a; red[(t >> 6) * 2 + 1] = vv; }
        __syncthreads();
        if (t == 0) {
            float A = 0.f, V = 0.f;
#pragma unroll
            for (int kk = 0; kk < 8; ++kk) { A += red[2 * kk]; V += red[2 * kk + 1]; }
            out[0] = 1.0f - A * rcp_fast(V);
        }
    }
}

extern "C" void kernel_launch(void* const* d_in, const int* in_sizes, int n_in,
                              void* d_out, int out_size, void* d_ws, size_t ws_size,
                              hipStream_t stream) {
    const float* x = (const float*)d_in[0];
    const int* tgt = (const int*)d_in[1];
    float* out = (float*)d_out;

    float* rs = (float*)d_ws;                                 // 1 MB
    float2* av = (float2*)((char*)d_ws + N * N * 4);          // 4 KB
    int* ticket = (int*)((char*)d_ws + N * N * 4 + N * 8);    // 4 B

    map_sim_kernel<<<dim3(32, 16), 256, 0, stream>>>(x, rs, ticket);
    map_ap_kernel<<<N, 512, 0, stream>>>(rs, tgt, av, ticket, out);
}